// Round 1
// baseline (280.008 us; speedup 1.0000x reference)
//
#include <hip/hip_runtime.h>
#include <cstdint>

// Problem constants (from reference)
#define BB 32
#define TV 8192
#define KK 64
#define TS 128
#define MARGIN_F 0.1f
#define LAMBDA_F 0.5f

// Workspace layout:
//   wsA : B*TV uint64  (2 MB)   bit k = (gt_mask[b,t,idx[k]]>0) && valid[b,t]
//   wsV : B*TV/64 uint64 (32 KB) bit (t%64) = valid[b,t]
//   acc : 1 float accumulator
static constexpr size_t WSA_OFF = 0;
static constexpr size_t WSV_OFF = (size_t)BB * TV * 8;
static constexpr size_t ACC_OFF = WSV_OFF + (size_t)BB * (TV / 64) * 8;

// ---------------------------------------------------------------------------
// Kernel 1: coalesced stream of gt_mask + ballot-transpose into packed masks.
// Each wave handles 64 consecutive rows (r = b*TV + t). Per iteration one
// int4/lane load covers 1024 B = 2 full rows of 128 ints.
// Row-0 col c lives in lane c>>2 component c&3 (ballot bit c>>2);
// Row-1 col c lives in lane 32+(c>>2) (ballot bit 32+(c>>2)).
// ---------------------------------------------------------------------------
__global__ __launch_bounds__(256) void pack_kernel(
    const int* __restrict__ gt, const int* __restrict__ mv,
    const int* __restrict__ idx,
    unsigned long long* __restrict__ wsA, unsigned long long* __restrict__ wsV) {
  const int lane = threadIdx.x & 63;
  const int wave = blockIdx.x * 4 + (threadIdx.x >> 6);
  const int r0 = wave * 64;            // 64 rows per wave; 1024 blocks covers B*TV
  const int c = idx[lane];             // this lane extracts column for k = lane
  const int csel = c & 3, csh = c >> 2;

  // validity bits for these 64 rows (same b: TV % 64 == 0)
  const unsigned long long V = __ballot(mv[r0 + lane] != 0);
  if (lane == 0) wsV[r0 >> 6] = V;

  const int4* rowp = (const int4*)(gt + (size_t)r0 * TS);
#pragma unroll 2
  for (int ch = 0; ch < 32; ++ch) {
    int4 v = rowp[ch * 64 + lane];
    unsigned long long b0 = __ballot(v.x > 0);
    unsigned long long b1 = __ballot(v.y > 0);
    unsigned long long b2 = __ballot(v.z > 0);
    unsigned long long b3 = __ballot(v.w > 0);
    unsigned long long sel = (csel == 0) ? b0 : (csel == 1) ? b1 : (csel == 2) ? b2 : b3;
    int raw0 = (int)((sel >> csh) & 1ull);          // gt>0 bit, row r0+2ch, col c
    int raw1 = (int)((sel >> (32 + csh)) & 1ull);   // row r0+2ch+1
    const int rlo = 2 * ch, rhi = 2 * ch + 1;
    const int v0 = (int)((V >> rlo) & 1ull);
    const int v1 = (int)((V >> rhi) & 1ull);
    unsigned long long A0 = __ballot(v0 & raw0);    // bit k = aligned(k, row rlo)
    unsigned long long A1 = __ballot(v1 & raw1);
    if (lane == 0) {
      wsA[r0 + rlo] = A0;
      wsA[r0 + rhi] = A1;
    }
  }
}

// ---------------------------------------------------------------------------
// Kernel 2: one block per (k,b). Streams pred_intervened coalesced (each
// element read exactly once from HBM); packed masks + pred_orig come from L2.
// non_aligned = valid && !aligned (valid folded into A already).
// ---------------------------------------------------------------------------
__global__ __launch_bounds__(256) void main_kernel(
    const float* __restrict__ po, const float* __restrict__ pi,
    const unsigned long long* __restrict__ wsA,
    const unsigned long long* __restrict__ wsV, float* __restrict__ acc) {
  const int k = blockIdx.x & (KK - 1);
  const int b = blockIdx.x >> 6;
  const float* pik = pi + ((size_t)k * BB + b) * TV;
  const float* pob = po + (size_t)b * TV;
  const unsigned long long* Ab = wsA + (size_t)b * TV;
  const unsigned long long* Vb = wsV + (size_t)b * (TV / 64);

  float ea = 0.f, en = 0.f;
  int ca = 0, cn = 0;
  for (int t = threadIdx.x; t < TV; t += 256) {
    const float xo = pob[t];
    const float xi = pik[t];
    const unsigned long long A = Ab[t];
    const int valid = (int)((Vb[t >> 6] >> (t & 63)) & 1ull);
    const int ab = (int)((A >> k) & 1ull);
    const int nb = valid & (ab ^ 1);
    const float so = 1.f / (1.f + __expf(-xo));
    const float si = 1.f / (1.f + __expf(-xi));
    const float eff = fabsf(so - si);
    ea += ab ? eff : 0.f;
    en += nb ? eff : 0.f;
    ca += ab;
    cn += nb;
  }
  // wave reduce (width 64)
#pragma unroll
  for (int off = 32; off > 0; off >>= 1) {
    ea += __shfl_down(ea, off);
    en += __shfl_down(en, off);
    ca += __shfl_down(ca, off);
    cn += __shfl_down(cn, off);
  }
  __shared__ float sea[4], sen[4];
  __shared__ int sca[4], scn[4];
  const int w = threadIdx.x >> 6;
  if ((threadIdx.x & 63) == 0) { sea[w] = ea; sen[w] = en; sca[w] = ca; scn[w] = cn; }
  __syncthreads();
  if (threadIdx.x == 0) {
    float EA = 0.f, EN = 0.f;
    int CA = 0, CN = 0;
#pragma unroll
    for (int i = 0; i < 4; ++i) { EA += sea[i]; EN += sen[i]; CA += sca[i]; CN += scn[i]; }
    float pp = 0.f;
    if (CA > 0 && CN > 0) {
      const float d = MARGIN_F - (EA / (float)CA - EN / (float)CN);
      pp = d > 0.f ? d : 0.f;
    }
    atomicAdd(acc, pp);
  }
}

__global__ void fin_kernel(const float* __restrict__ acc, float* __restrict__ out) {
  const float s = acc[0] * (1.0f / (float)(BB * KK));
  out[0] = s;
  out[1] = s * LAMBDA_F;
}

extern "C" void kernel_launch(void* const* d_in, const int* in_sizes, int n_in,
                              void* d_out, int out_size, void* d_ws, size_t ws_size,
                              hipStream_t stream) {
  const float* pred_orig = (const float*)d_in[0];       // [B,TV] fp32
  const float* pred_int  = (const float*)d_in[1];       // [K,B,TV] fp32
  const int*   idx       = (const int*)d_in[2];         // [K] int32
  const int*   gt        = (const int*)d_in[3];         // [B,TV,TS] int32
  const int*   mv        = (const int*)d_in[4];         // [B,TV] int32
  float* out = (float*)d_out;

  char* ws = (char*)d_ws;
  unsigned long long* wsA = (unsigned long long*)(ws + WSA_OFF);
  unsigned long long* wsV = (unsigned long long*)(ws + WSV_OFF);
  float* acc = (float*)(ws + ACC_OFF);

  hipMemsetAsync(acc, 0, sizeof(float), stream);  // ws is re-poisoned each call
  pack_kernel<<<1024, 256, 0, stream>>>(gt, mv, idx, wsA, wsV);
  main_kernel<<<BB * KK, 256, 0, stream>>>(pred_orig, pred_int, wsA, wsV, acc);
  fin_kernel<<<1, 1, 0, stream>>>(acc, out);
}